// Round 1
// baseline (553.608 us; speedup 1.0000x reference)
//
#include <hip/hip_runtime.h>

// TernaryLinear: out = x @ (sign(W1)-sign(W2)).T + (b1-b2)
// M=8192 tokens, N=4096 out, K=4096 in. One f16-MFMA GEMM after folding.

#define DIM_K 4096
#define DIM_N 4096
#define DIM_M 8192

typedef _Float16 f16x8 __attribute__((ext_vector_type(8)));
typedef _Float16 f16x4 __attribute__((ext_vector_type(4)));
typedef float    f32x4 __attribute__((ext_vector_type(4)));

// ---------------- conversion kernels ----------------

__global__ void cvt_x_kernel(const float4* __restrict__ x, f16x4* __restrict__ xh) {
    const int i = blockIdx.x * blockDim.x + threadIdx.x;
    const float4 v = x[i];
    f16x4 h;
    h[0] = (_Float16)v.x; h[1] = (_Float16)v.y;
    h[2] = (_Float16)v.z; h[3] = (_Float16)v.w;
    xh[i] = h;
}

__device__ __forceinline__ float signdiff(float a, float b) {
    const float sa = (float)((a > 0.f) - (a < 0.f));
    const float sb = (float)((b > 0.f) - (b < 0.f));
    return sa - sb; // in {-2,-1,0,1,2}, exact in fp16
}

__global__ void cvt_w_kernel(const float4* __restrict__ w1,
                             const float4* __restrict__ w2,
                             f16x4* __restrict__ wh) {
    const int i = blockIdx.x * blockDim.x + threadIdx.x;
    const float4 a = w1[i];
    const float4 b = w2[i];
    f16x4 h;
    h[0] = (_Float16)signdiff(a.x, b.x);
    h[1] = (_Float16)signdiff(a.y, b.y);
    h[2] = (_Float16)signdiff(a.z, b.z);
    h[3] = (_Float16)signdiff(a.w, b.w);
    wh[i] = h;
}

__global__ void cvt_b_kernel(const float* __restrict__ b1,
                             const float* __restrict__ b2,
                             float* __restrict__ bd) {
    const int i = blockIdx.x * blockDim.x + threadIdx.x;
    bd[i] = b1[i] - b2[i];
}

// ---------------- GEMM ----------------
// C[m,n] = sum_k Xh[m,k] * Wh[n,k] + bd[n]
// 128x128 tile, BK=64 (128 B/row), 256 threads = 4 waves in 2x2 (64x64 each).
// Staging: global_load_lds dwordx4; LDS dest is wave-uniform base + lane*16,
// so the bank-conflict swizzle (chunk ^= row&7) is applied to the GLOBAL
// source address, not the LDS dest.
// LDS: A tile [128][64] f16 at 0, B tile at 16384. 32 KiB total.

__global__ __launch_bounds__(256, 2) void ternary_gemm(
    const _Float16* __restrict__ Xh, const _Float16* __restrict__ Wh,
    const float* __restrict__ bd, float* __restrict__ C) {
    __shared__ __align__(16) char smem[32768];

    const int tid  = threadIdx.x;
    const int wave = tid >> 6;
    const int lane = tid & 63;
    const int wm = wave >> 1, wn = wave & 1;   // 2x2 wave grid
    const int q = lane >> 4, r = lane & 15;    // MFMA lane coords

    // ---- staging geometry (per lane) ----
    const int lrow   = lane >> 3;          // 0..7   row within wave's 8-row slab
    const int lchunk = lane & 7;           // 0..7   16B chunk within 128B row
    const int gchunk = lchunk ^ lrow;      // source swizzle: row&7 == lrow here
    const int srow   = wave * 8 + lrow;    // 0..31  row within one 32-row issue

    const int bRowM = blockIdx.y * 128;
    const int bColN = blockIdx.x * 128;

    const char* aPtr = (const char*)Xh + (size_t)(bRowM + srow) * (DIM_K * 2) + gchunk * 16;
    const char* bPtr = (const char*)Wh + (size_t)(bColN + srow) * (DIM_K * 2) + gchunk * 16;

    char* const ldsA = smem + wave * 1024;
    char* const ldsB = smem + 16384 + wave * 1024;

    // ---- compute-side LDS read bases ----
    // A frag (im,kk): row = wm*64+im*16+r, stored chunk = (kk*4+q) ^ (r&7)
    const char* const aRd = smem + (wm * 64 + r) * 128;
    const char* const bRd = smem + 16384 + (wn * 64 + r) * 128;
    const int sc0 = ((0 * 4 + q) ^ (r & 7)) * 16;
    const int sc1 = ((1 * 4 + q) ^ (r & 7)) * 16;

    f32x4 acc[4][4] = {};

    for (int kt = 0; kt < DIM_K; kt += 64) {
        __syncthreads();  // prev compute reads done before LDS overwrite
#pragma unroll
        for (int i = 0; i < 4; ++i) {
            __builtin_amdgcn_global_load_lds(
                (const __attribute__((address_space(1))) void*)(aPtr + (size_t)i * 262144),
                (__attribute__((address_space(3))) void*)(ldsA + i * 4096), 16, 0, 0);
            __builtin_amdgcn_global_load_lds(
                (const __attribute__((address_space(1))) void*)(bPtr + (size_t)i * 262144),
                (__attribute__((address_space(3))) void*)(ldsB + i * 4096), 16, 0, 0);
        }
        __syncthreads();  // drains vmcnt(0) before any wave reads LDS

#pragma unroll
        for (int kk = 0; kk < 2; ++kk) {
            const int sc = kk ? sc1 : sc0;
            f16x8 af[4], bf[4];
#pragma unroll
            for (int t = 0; t < 4; ++t) {
                af[t] = *(const f16x8*)(aRd + t * 2048 + sc);
                bf[t] = *(const f16x8*)(bRd + t * 2048 + sc);
            }
#pragma unroll
            for (int im = 0; im < 4; ++im)
#pragma unroll
                for (int in = 0; in < 4; ++in)
                    acc[im][in] = __builtin_amdgcn_mfma_f32_16x16x32_f16(
                        af[im], bf[in], acc[im][in], 0, 0, 0);
        }
        aPtr += 128;  // advance 64 halves in K
        bPtr += 128;
    }

    // ---- epilogue: C/D layout col=lane&15, row=q*4+reg ----
    const int col0 = bColN + wn * 64 + r;
    const int row0 = bRowM + wm * 64 + q * 4;
    float bias[4];
#pragma unroll
    for (int in = 0; in < 4; ++in) bias[in] = bd[col0 + in * 16];
#pragma unroll
    for (int im = 0; im < 4; ++im) {
#pragma unroll
        for (int in = 0; in < 4; ++in) {
            const f32x4 v = acc[im][in];
            const int col = col0 + in * 16;
            const size_t base = (size_t)(row0 + im * 16) * DIM_N + col;
#pragma unroll
            for (int j = 0; j < 4; ++j)
                C[base + (size_t)j * DIM_N] = v[j] + bias[in];
        }
    }
}

// ---------------- launch ----------------

extern "C" void kernel_launch(void* const* d_in, const int* in_sizes, int n_in,
                              void* d_out, int out_size, void* d_ws, size_t ws_size,
                              hipStream_t stream) {
    const float* x  = (const float*)d_in[0];
    const float* W1 = (const float*)d_in[1];
    const float* W2 = (const float*)d_in[2];
    const float* b1 = (const float*)d_in[3];
    const float* b2 = (const float*)d_in[4];
    float* out = (float*)d_out;

    // workspace layout: Xh (64 MiB) | Wh (32 MiB) | bd (16 KiB)  => ~96 MiB
    _Float16* Xh = (_Float16*)d_ws;
    _Float16* Wh = (_Float16*)((char*)d_ws + (size_t)67108864);
    float*    bd = (float*)((char*)d_ws + (size_t)67108864 + 33554432);
    (void)ws_size; (void)in_sizes; (void)n_in; (void)out_size;

    // x -> f16 : 8192*4096/4 = 8388608 float4s
    cvt_x_kernel<<<32768, 256, 0, stream>>>((const float4*)x, (f16x4*)Xh);
    // Wd = sign(W1)-sign(W2) -> f16 : 4096*4096/4 float4s
    cvt_w_kernel<<<16384, 256, 0, stream>>>((const float4*)W1, (const float4*)W2, (f16x4*)Wh);
    // bd = b1-b2
    cvt_b_kernel<<<16, 256, 0, stream>>>(b1, b2, bd);

    // GEMM: grid (N/128, M/128) = (32, 64)
    ternary_gemm<<<dim3(32, 64), 256, 0, stream>>>(Xh, Wh, bd, out);
}